// Round 5
// baseline (151.219 us; speedup 1.0000x reference)
//
#include <hip/hip_runtime.h>
#include <hip/hip_bf16.h>

#define NB    8192
#define NEI   64
#define DIM   128
#define D2    256
#define NR_W  1001   // 2*CNT_R+1
#define NR_Z  1000   // 2*CNT_R
#define EPB_LD 136   // bf16 elems per LDS row (128 + 8 pad) -> verified conflict-free
#define BPB   16     // b's per block; grid = 512 = 2 blocks/CU
#define C2L2E 2.8853900817779268f   // 2*log2(e): exp(2v) = exp2(C2L2E*v)

typedef __attribute__((ext_vector_type(8))) short bf16x8;   // 8 bf16 = 4 VGPR
typedef __attribute__((ext_vector_type(4))) float f32x4;

__device__ __forceinline__ ushort f2bf(float x) {
    union { float f; unsigned u; } c; c.f = x;
    unsigned u = c.u;
    return (ushort)((u + 0x7fffu + ((u >> 16) & 1u)) >> 16);   // RNE
}

__device__ __forceinline__ unsigned pk2(float a, float b) {
    __hip_bfloat162 h = __float22bfloat162_rn(make_float2(a, b));  // v_cvt_pk_bf16_f32
    return *(unsigned*)&h;
}

__device__ __forceinline__ void gll16(const void* g, void* l) {
    __builtin_amdgcn_global_load_lds(
        (const __attribute__((address_space(1))) unsigned int*)g,
        (__attribute__((address_space(3))) unsigned int*)l, 16, 0, 0);
}

// ---------------- precompute kernels ----------------

__global__ void k_norm(const float* __restrict__ w_r_table, float* __restrict__ norm_t) {
    int r = blockIdx.x;          // 0..1000
    int t = threadIdx.x;         // 0..127
    float v = w_r_table[r * DIM + t];
    float s = v * v;
    #pragma unroll
    for (int m = 1; m < 64; m <<= 1) s += __shfl_xor(s, m);
    __shared__ float sh[2];
    if ((t & 63) == 0) sh[t >> 6] = s;
    __syncthreads();
    float tot = sh[0] + sh[1];
    norm_t[r * DIM + t] = v / sqrtf(tot);
}

// Tq[r][o] = attn_W_b[o] + sum_{k<128} attn_W_w[o][k] * zq_table[r][k]
__global__ void k_tq(const float* __restrict__ zq_table, const float* __restrict__ W,
                     const float* __restrict__ bias, float* __restrict__ tq_t) {
    int r = blockIdx.x;          // 0..999
    int o = threadIdx.x;         // 0..255
    __shared__ float4 z4[32];
    if (o < 32) z4[o] = ((const float4*)(zq_table + r * DIM))[o];
    __syncthreads();
    const float4* wr = (const float4*)(W + o * D2);
    float acc = bias[o];
    #pragma unroll 8
    for (int i = 0; i < 32; ++i) {
        float4 wv = wr[i], zv = z4[i];
        acc += wv.x*zv.x + wv.y*zv.y + wv.z*zv.z + wv.w*zv.w;
    }
    tq_t[r * D2 + o] = acc;
}

// B fragments in mfma_16x16x32_bf16 order (layout verified rounds 2-4):
// bfrag[((ot*4+kt)*64 + lane)*8 + j] = W2[k][o], o = ot*16+(lane&15), k = kt*32+(lane>>4)*8+j
__global__ void k_bfrag(const float* __restrict__ W, ushort* __restrict__ bfrag) {
    int ot = blockIdx.x;         // 0..15
    int kt = blockIdx.y;         // 0..3
    int l  = threadIdx.x;        // 0..63
    int o  = ot * 16 + (l & 15);
    int k  = kt * 32 + (l >> 4) * 8;
    const float4* src = (const float4*)(W + o * D2 + DIM + k);
    float4 a = src[0], c = src[1];
    uint4 w;
    w.x = f2bf(a.x) | ((unsigned)f2bf(a.y) << 16);
    w.y = f2bf(a.z) | ((unsigned)f2bf(a.w) << 16);
    w.z = f2bf(c.x) | ((unsigned)f2bf(c.y) << 16);
    w.w = f2bf(c.z) | ((unsigned)f2bf(c.w) << 16);
    *(uint4*)(bfrag + ((ot * 4 + kt) * 64 + l) * 8) = w;
}

// SUA = sum(u_a_w)  (alpha = SUA - 2*sum(ua*r), r = sigmoid-like term)
__global__ void k_sua(const float* __restrict__ u, float* __restrict__ sua) {
    int t = threadIdx.x;         // 0..255
    float v = u[t];
    #pragma unroll
    for (int m = 1; m < 64; m <<= 1) v += __shfl_xor(v, m);
    __shared__ float sh[4];
    if ((t & 63) == 0) sh[t >> 6] = v;
    __syncthreads();
    if (t == 0) sua[0] = sh[0] + sh[1] + sh[2] + sh[3];
}

// ---------------- main fused kernel ----------------
// 512 threads (8 waves), BPB b's per block. Pipeline per b:
//   proj (reads e_raw LDS + norm L2) -> barrier1 -> [stage e(b+1) via
//   global_load_lds + reg-prefetch rid/tq/rw] MFMA+epilogue -> barrier2
//   (drains gll) -> softmax/store -> rotate.
// B-fragments (32 VGPR/wave) pinned with empty asm so the compiler cannot
// sink the loads into the loop (round-4 failure: L2 reload stream per mt).

__global__ __launch_bounds__(512, 4) void k_main(
    const float* __restrict__ e_emb,    // (B,64,128)
    const float* __restrict__ rw,       // (B,64)
    const int*   __restrict__ nei_rid,  // (B,64)
    const int*   __restrict__ q_rid,    // (B,)
    const float* __restrict__ norm_t,   // (1001,128)
    const float* __restrict__ tq_t,     // (1000,256)
    const ushort* __restrict__ bfrag,   // (16,4,64,8) bf16
    const float* __restrict__ u_a_sum,  // scalar SUA
    const float* __restrict__ u_a_w,    // (256,)
    float* __restrict__ out)            // (B,64)
{
    __shared__ __align__(16) float  e_raw[NEI * DIM];    // 32768 B, swizzled blocks
    __shared__ __align__(16) ushort ep16[NEI * EPB_LD];  // 17408 B
    __shared__ float alpw[8][NEI];                       // 2048 B

    const int t    = threadIdx.x;
    const int wave = t >> 6, lane = t & 63;
    const int ln   = lane & 15, hi = lane >> 4;
    const int row  = t >> 3, q3 = t & 7;                 // proj: 8 lanes/row
    const int b0   = blockIdx.x * BPB;

    // ---- pinned B fragments: this wave's 32 output cols (2 ot x 4 kt) ----
    bf16x8 bfr_[2][4];
    #pragma unroll
    for (int nt = 0; nt < 2; ++nt)
        #pragma unroll
        for (int kt = 0; kt < 4; ++kt)
            bfr_[nt][kt] = *(const bf16x8*)(bfrag + ((((wave*2+nt)*4 + kt)*64 + lane)*8));
    asm volatile("" : "+v"(bfr_[0][0]), "+v"(bfr_[0][1]), "+v"(bfr_[0][2]), "+v"(bfr_[0][3]),
                      "+v"(bfr_[1][0]), "+v"(bfr_[1][1]), "+v"(bfr_[1][2]), "+v"(bfr_[1][3]));

    float ua2[2];
    #pragma unroll
    for (int nt = 0; nt < 2; ++nt) ua2[nt] = u_a_w[wave*32 + nt*16 + ln];
    asm volatile("" : "+v"(ua2[0]), "+v"(ua2[1]));
    const float sua = u_a_sum[0];

    // ---- per-lane swizzled staging source offsets (4 gll calls/wave) ----
    // LDS dest (linear, wave-uniform + lane*16): D = wave*4096 + c*1024 + lane*16
    // global src byte = D ^ ((row(D)&7)<<4); read side XORs the same -> identity.
    unsigned soff[4];
    #pragma unroll
    for (int c = 0; c < 4; ++c) {
        unsigned D = (unsigned)(wave*4096 + c*1024 + lane*16);
        unsigned r7 = (unsigned)((wave*8 + 2*c + (lane>>5)) & 7);
        soff[c] = D ^ (r7 << 4);
    }
    const char* ebase = (const char*)e_emb;

    // ---- stage b0 + prefetch its scalars ----
    #pragma unroll
    for (int c = 0; c < 4; ++c)
        gll16(ebase + (((size_t)b0) << 15) + soff[c], (char*)e_raw + wave*4096 + c*1024);
    int   rid_c = nei_rid[b0 * NEI + row];
    float rw_c  = rw[(size_t)b0 * NEI + (t & 63)];
    float tqc[2];
    {
        int qr = q_rid[b0];
        #pragma unroll
        for (int nt = 0; nt < 2; ++nt)
            tqc[nt] = C2L2E * tq_t[qr * D2 + wave*32 + nt*16 + ln];
    }
    int   rid_n = 0;  float rw_n = 0.f;  float tqn[2] = {0.f, 0.f};

    __syncthreads();   // drains gll: e_raw(b0) staged

    #pragma unroll 1
    for (int i = 0; i < BPB; ++i) {
        const int b = b0 + i;

        // ---- projection: 8 lanes/row, e from swizzled LDS, n from L2 ----
        {
            const float4* nsrc = (const float4*)(norm_t + rid_c * DIM + q3 * 16);
            float4 nv[4];
            #pragma unroll
            for (int k = 0; k < 4; ++k) nv[k] = nsrc[k];
            const unsigned rbase = (unsigned)(row * 512 + q3 * 64);
            const unsigned rx = (unsigned)((row & 7) << 4);
            float4 ev[4];
            #pragma unroll
            for (int k = 0; k < 4; ++k)
                ev[k] = *(const float4*)((const char*)e_raw + ((rbase + k*16) ^ rx));
            float part = 0.f;
            #pragma unroll
            for (int k = 0; k < 4; ++k)
                part += ev[k].x*nv[k].x + ev[k].y*nv[k].y + ev[k].z*nv[k].z + ev[k].w*nv[k].w;
            part += __shfl_xor(part, 1);
            part += __shfl_xor(part, 2);
            part += __shfl_xor(part, 4);
            const float d = part;                 // full-row e . n
            float p0 = fmaf(-d, nv[0].x, ev[0].x), p1 = fmaf(-d, nv[0].y, ev[0].y);
            float p2 = fmaf(-d, nv[0].z, ev[0].z), p3 = fmaf(-d, nv[0].w, ev[0].w);
            float p4 = fmaf(-d, nv[1].x, ev[1].x), p5 = fmaf(-d, nv[1].y, ev[1].y);
            float p6 = fmaf(-d, nv[1].z, ev[1].z), p7 = fmaf(-d, nv[1].w, ev[1].w);
            uint4 w0; w0.x = pk2(p0,p1); w0.y = pk2(p2,p3); w0.z = pk2(p4,p5); w0.w = pk2(p6,p7);
            float s0 = fmaf(-d, nv[2].x, ev[2].x), s1 = fmaf(-d, nv[2].y, ev[2].y);
            float s2 = fmaf(-d, nv[2].z, ev[2].z), s3 = fmaf(-d, nv[2].w, ev[2].w);
            float s4 = fmaf(-d, nv[3].x, ev[3].x), s5 = fmaf(-d, nv[3].y, ev[3].y);
            float s6 = fmaf(-d, nv[3].z, ev[3].z), s7 = fmaf(-d, nv[3].w, ev[3].w);
            uint4 w1; w1.x = pk2(s0,s1); w1.y = pk2(s2,s3); w1.z = pk2(s4,s5); w1.w = pk2(s6,s7);
            char* dst = (char*)ep16 + row * (EPB_LD*2) + q3 * 32;
            *(uint4*)dst = w0;
            *(uint4*)(dst + 16) = w1;
        }

        __syncthreads();   // #1: ep16 ready, e_raw fully consumed

        // ---- stage e(b+1) into e_raw + reg-prefetch scalars (hidden by MFMA) ----
        if (i + 1 < BPB) {
            const size_t ebo = ((size_t)(b + 1)) << 15;
            #pragma unroll
            for (int c = 0; c < 4; ++c)
                gll16(ebase + ebo + soff[c], (char*)e_raw + wave*4096 + c*1024);
            rid_n = nei_rid[(b + 1) * NEI + row];
            rw_n  = rw[(size_t)(b + 1) * NEI + (t & 63)];
            int qr1 = q_rid[b + 1];
            #pragma unroll
            for (int nt = 0; nt < 2; ++nt)
                tqn[nt] = tq_t[qr1 * D2 + wave*32 + nt*16 + ln];
        }

        // ---- MFMA + fused epilogue per M-tile ----
        #pragma unroll
        for (int mt = 0; mt < 4; ++mt) {
            bf16x8 a_[4];
            #pragma unroll
            for (int kt = 0; kt < 4; ++kt)
                a_[kt] = *(const bf16x8*)&ep16[(mt*16 + ln) * EPB_LD + kt*32 + hi*8];
            f32x4 acc[2];
            #pragma unroll
            for (int nt = 0; nt < 2; ++nt) acc[nt] = (f32x4){0.f, 0.f, 0.f, 0.f};
            #pragma unroll
            for (int kt = 0; kt < 4; ++kt)
                #pragma unroll
                for (int nt = 0; nt < 2; ++nt)
                    acc[nt] = __builtin_amdgcn_mfma_f32_16x16x32_bf16(a_[kt], bfr_[nt][kt], acc[nt], 0, 0, 0);
            // C/D: col = ln, row = mt*16 + hi*4 + j. alpha = SUA - 2*sum(ua*r)
            float pr[4] = {0.f, 0.f, 0.f, 0.f};
            #pragma unroll
            for (int nt = 0; nt < 2; ++nt)
                #pragma unroll
                for (int j = 0; j < 4; ++j) {
                    float e2 = __builtin_exp2f(fmaf(C2L2E, acc[nt][j], tqc[nt]));
                    float r  = __builtin_amdgcn_rcpf(e2 + 1.f);
                    pr[j] = fmaf(ua2[nt], r, pr[j]);
                }
            #pragma unroll
            for (int m = 1; m < 16; m <<= 1)            // xor 1/2/4/8 -> DPP
                #pragma unroll
                for (int j = 0; j < 4; ++j) pr[j] += __shfl_xor(pr[j], m);
            if (ln == 0) {
                #pragma unroll
                for (int j = 0; j < 4; ++j) alpw[wave][mt*16 + hi*4 + j] = pr[j];
            }
        }

        __syncthreads();   // #2: alpw ready, ep16 free, gll(b+1) drained

        // ---- softmax + rw (shift-invariant, logits bounded by SUA±2*sum|ua|) ----
        if (t < NEI) {
            float s8 = 0.f;
            #pragma unroll
            for (int w = 0; w < 8; ++w) s8 += alpw[w][t];
            float a = fmaf(-2.f, s8, sua);
            float p = __expf(a);
            float s = p;
            #pragma unroll
            for (int m = 1; m < 64; m <<= 1) s += __shfl_xor(s, m);
            out[(size_t)b * NEI + t] = fmaf(p, __builtin_amdgcn_rcpf(s), rw_c);
        }

        // ---- rotate prefetched state (vmcnt already drained by barrier #2) ----
        if (i + 1 < BPB) {
            rid_c = rid_n;
            rw_c  = rw_n;
            tqc[0] = C2L2E * tqn[0];
            tqc[1] = C2L2E * tqn[1];
            asm volatile("" : "+v"(rid_c), "+v"(rw_c), "+v"(tqc[0]), "+v"(tqc[1]));
        }
    }
}

// ---------------- launch ----------------

extern "C" void kernel_launch(void* const* d_in, const int* in_sizes, int n_in,
                              void* d_out, int out_size, void* d_ws, size_t ws_size,
                              hipStream_t stream) {
    const float* e_emb   = (const float*)d_in[0];
    const float* rw      = (const float*)d_in[1];
    const float* w_r_tab = (const float*)d_in[2];
    const float* zq_tab  = (const float*)d_in[3];
    const float* attn_W  = (const float*)d_in[4];
    const float* attn_b  = (const float*)d_in[5];
    const float* u_a_w   = (const float*)d_in[6];
    // d_in[7] = u_a_b: cancels in softmax, unused
    const int*   nei_rid = (const int*)d_in[8];
    const int*   q_rid   = (const int*)d_in[9];
    float* out = (float*)d_out;

    float* ws = (float*)d_ws;
    float* norm_t = ws;                             // 1001*128 f32
    float* tq_t   = norm_t + NR_W * DIM;            // 1000*256 f32
    ushort* bfrag = (ushort*)(tq_t + NR_Z * D2);    // 16*4*64*8 bf16
    float* suap   = (float*)(bfrag + 16*4*64*8);    // 1 f32

    k_norm<<<NR_W, DIM, 0, stream>>>(w_r_tab, norm_t);
    k_tq<<<NR_Z, D2, 0, stream>>>(zq_tab, attn_W, attn_b, tq_t);
    k_bfrag<<<dim3(16, 4), 64, 0, stream>>>(attn_W, bfrag);
    k_sua<<<1, 256, 0, stream>>>(u_a_w, suap);
    k_main<<<NB / BPB, 512, 0, stream>>>(e_emb, rw, nei_rid, q_rid,
                                         norm_t, tq_t, bfrag, suap, u_a_w, out);
}

// Round 6
// 143.739 us; speedup vs baseline: 1.0520x; 1.0520x over previous
//
#include <hip/hip_runtime.h>
#include <hip/hip_bf16.h>

#define NB    8192
#define NEI   64
#define DIM   128
#define D2    256
#define NR_W  1001   // 2*CNT_R+1
#define NR_Z  1000   // 2*CNT_R
#define EPB_LD 136   // bf16 elems per LDS row (128 + 8 pad)
#define BPB   2      // b's per block; grid = 4096
#define C2L2E 2.8853900817779268f   // 2*log2(e): exp(2v) = exp2(C2L2E*v)

typedef __attribute__((ext_vector_type(8))) short bf16x8;   // 8 bf16 = 4 VGPR
typedef __attribute__((ext_vector_type(4))) float f32x4;

__device__ __forceinline__ ushort f2bf(float x) {
    union { float f; unsigned u; } c; c.f = x;
    unsigned u = c.u;
    return (ushort)((u + 0x7fffu + ((u >> 16) & 1u)) >> 16);   // RNE
}

__device__ __forceinline__ unsigned pk2(float a, float b) {
    __hip_bfloat162 h = __float22bfloat162_rn(make_float2(a, b));  // v_cvt_pk_bf16_f32
    return *(unsigned*)&h;
}

// ---------------- precompute kernels ----------------

__global__ void k_norm(const float* __restrict__ w_r_table, float* __restrict__ norm_t) {
    int r = blockIdx.x;          // 0..1000
    int t = threadIdx.x;         // 0..127
    float v = w_r_table[r * DIM + t];
    float s = v * v;
    #pragma unroll
    for (int m = 1; m < 64; m <<= 1) s += __shfl_xor(s, m);
    __shared__ float sh[2];
    if ((t & 63) == 0) sh[t >> 6] = s;
    __syncthreads();
    float tot = sh[0] + sh[1];
    norm_t[r * DIM + t] = v / sqrtf(tot);
}

// Tq[r][o] = attn_W_b[o] + sum_{k<128} attn_W_w[o][k] * zq_table[r][k]
__global__ void k_tq(const float* __restrict__ zq_table, const float* __restrict__ W,
                     const float* __restrict__ bias, float* __restrict__ tq_t) {
    int r = blockIdx.x;          // 0..999
    int o = threadIdx.x;         // 0..255
    __shared__ float4 z4[32];
    if (o < 32) z4[o] = ((const float4*)(zq_table + r * DIM))[o];
    __syncthreads();
    const float4* wr = (const float4*)(W + o * D2);
    float acc = bias[o];
    #pragma unroll 8
    for (int i = 0; i < 32; ++i) {
        float4 wv = wr[i], zv = z4[i];
        acc += wv.x*zv.x + wv.y*zv.y + wv.z*zv.z + wv.w*zv.w;
    }
    tq_t[r * D2 + o] = acc;
}

// B fragments in mfma_16x16x32_bf16 order (layout verified rounds 2-5):
// bfrag[((ot*4+kt)*64 + lane)*8 + j] = W2[k][o], o = ot*16+(lane&15), k = kt*32+(lane>>4)*8+j
__global__ void k_bfrag(const float* __restrict__ W, ushort* __restrict__ bfrag) {
    int ot = blockIdx.x;         // 0..15
    int kt = blockIdx.y;         // 0..3
    int l  = threadIdx.x;        // 0..63
    int o  = ot * 16 + (l & 15);
    int k  = kt * 32 + (l >> 4) * 8;
    const float4* src = (const float4*)(W + o * D2 + DIM + k);
    float4 a = src[0], c = src[1];
    uint4 w;
    w.x = f2bf(a.x) | ((unsigned)f2bf(a.y) << 16);
    w.y = f2bf(a.z) | ((unsigned)f2bf(a.w) << 16);
    w.z = f2bf(c.x) | ((unsigned)f2bf(c.y) << 16);
    w.w = f2bf(c.z) | ((unsigned)f2bf(c.w) << 16);
    *(uint4*)(bfrag + ((ot * 4 + kt) * 64 + l) * 8) = w;
}

// SUA = sum(u_a_w)  (alpha = SUA - 2*sum(ua*r))
__global__ void k_sua(const float* __restrict__ u, float* __restrict__ sua) {
    int t = threadIdx.x;         // 0..255
    float v = u[t];
    #pragma unroll
    for (int m = 1; m < 64; m <<= 1) v += __shfl_xor(v, m);
    __shared__ float sh[4];
    if ((t & 63) == 0) sh[t >> 6] = v;
    __syncthreads();
    if (t == 0) sua[0] = sh[0] + sh[1] + sh[2] + sh[3];
}

// ---------------- main fused kernel ----------------
// 512 threads / 8 waves, each wave owns 32 output cols -> B fragments are
// only 32 VGPR/wave and stay resident (R5 evidence: VGPR_Count=64 at this
// slice size; R4's 64-col slices got rematerialized into L2 reloads).
// One pass covers all 64 rows at 8 lanes/row (ev/nv = 16+16 VGPR).
// BPB=2, grid=4096: plenty of independent blocks -> TLP hides e-load and
// norm-gather latency (R5's lockstep 2-blocks/CU pipeline lost to this).

__global__ __launch_bounds__(512, 4) void k_main(
    const float* __restrict__ e_emb,    // (B,64,128)
    const float* __restrict__ rw,       // (B,64)
    const int*   __restrict__ nei_rid,  // (B,64)
    const int*   __restrict__ q_rid,    // (B,)
    const float* __restrict__ norm_t,   // (1001,128)
    const float* __restrict__ tq_t,     // (1000,256)
    const ushort* __restrict__ bfrag,   // (16,4,64,8) bf16
    const float* __restrict__ u_a_sum,  // scalar SUA
    const float* __restrict__ u_a_w,    // (256,)
    float* __restrict__ out)            // (B,64)
{
    __shared__ __align__(16) ushort ep16[NEI * EPB_LD];  // 17408 B
    __shared__ float alpw[8][NEI];                       // 2048 B

    const int t    = threadIdx.x;
    const int wave = t >> 6, lane = t & 63;
    const int ln   = lane & 15, hi = lane >> 4;
    const int row  = t >> 3, q3 = t & 7;                 // proj: 8 lanes/row
    const int b0   = blockIdx.x * BPB;

    // ---- resident per-wave constants ----
    bf16x8 bfr_[2][4];                                   // 32 VGPR
    #pragma unroll
    for (int nt = 0; nt < 2; ++nt)
        #pragma unroll
        for (int kt = 0; kt < 4; ++kt)
            bfr_[nt][kt] = *(const bf16x8*)(bfrag + ((((wave*2+nt)*4 + kt)*64 + lane)*8));
    asm volatile("" : "+v"(bfr_[0][0]), "+v"(bfr_[0][1]), "+v"(bfr_[0][2]), "+v"(bfr_[0][3]),
                      "+v"(bfr_[1][0]), "+v"(bfr_[1][1]), "+v"(bfr_[1][2]), "+v"(bfr_[1][3]));
    float ua2[2];
    #pragma unroll
    for (int nt = 0; nt < 2; ++nt) ua2[nt] = u_a_w[wave*32 + nt*16 + ln];
    asm volatile("" : "+v"(ua2[0]), "+v"(ua2[1]));
    const float sua = u_a_sum[0];

    #pragma unroll 1
    for (int i = 0; i < BPB; ++i) {
        const int b = b0 + i;

        // ---- load e row-slice + norm row-slice, project, write bf16 LDS ----
        {
            const int rid = nei_rid[b * NEI + row];
            const float4* esrc = (const float4*)(e_emb + ((size_t)b * NEI + row) * DIM);
            const float4* nsrc = (const float4*)(norm_t + rid * DIM);
            float4 ev[4], nv[4];
            #pragma unroll
            for (int kk = 0; kk < 4; ++kk) {
                ev[kk] = esrc[q3 + 8*kk];     // 128B-contiguous per 8-lane group
                nv[kk] = nsrc[q3 + 8*kk];
            }
            float part = 0.f;
            #pragma unroll
            for (int kk = 0; kk < 4; ++kk)
                part += ev[kk].x*nv[kk].x + ev[kk].y*nv[kk].y + ev[kk].z*nv[kk].z + ev[kk].w*nv[kk].w;
            part += __shfl_xor(part, 1);
            part += __shfl_xor(part, 2);
            part += __shfl_xor(part, 4);
            const float d = part;             // full-row e . n
            #pragma unroll
            for (int kk = 0; kk < 4; ++kk) {
                float p0 = fmaf(-d, nv[kk].x, ev[kk].x);
                float p1 = fmaf(-d, nv[kk].y, ev[kk].y);
                float p2 = fmaf(-d, nv[kk].z, ev[kk].z);
                float p3 = fmaf(-d, nv[kk].w, ev[kk].w);
                uint2 w2; w2.x = pk2(p0, p1); w2.y = pk2(p2, p3);
                *(uint2*)((char*)ep16 + row * (EPB_LD*2) + (q3 + 8*kk) * 8) = w2;
            }
        }

        // per-b epilogue constants (2 loads, L2-hot)
        float tq2[2];
        {
            int qr = q_rid[b];
            #pragma unroll
            for (int nt = 0; nt < 2; ++nt)
                tq2[nt] = C2L2E * tq_t[qr * D2 + wave*32 + nt*16 + ln];
        }

        __syncthreads();   // #1: ep16 ready

        // ---- MFMA + fused epilogue per M-tile ----
        #pragma unroll
        for (int mt = 0; mt < 4; ++mt) {
            bf16x8 a_[4];
            #pragma unroll
            for (int kt = 0; kt < 4; ++kt)
                a_[kt] = *(const bf16x8*)&ep16[(mt*16 + ln) * EPB_LD + kt*32 + hi*8];
            f32x4 acc[2];
            #pragma unroll
            for (int nt = 0; nt < 2; ++nt) acc[nt] = (f32x4){0.f, 0.f, 0.f, 0.f};
            #pragma unroll
            for (int kt = 0; kt < 4; ++kt)
                #pragma unroll
                for (int nt = 0; nt < 2; ++nt)
                    acc[nt] = __builtin_amdgcn_mfma_f32_16x16x32_bf16(a_[kt], bfr_[nt][kt], acc[nt], 0, 0, 0);
            // C/D: col = ln, row = mt*16 + hi*4 + j
            float pr[4] = {0.f, 0.f, 0.f, 0.f};
            #pragma unroll
            for (int nt = 0; nt < 2; ++nt)
                #pragma unroll
                for (int j = 0; j < 4; ++j) {
                    float e2 = __builtin_exp2f(fmaf(C2L2E, acc[nt][j], tq2[nt]));
                    float r  = __builtin_amdgcn_rcpf(e2 + 1.f);
                    pr[j] = fmaf(ua2[nt], r, pr[j]);
                }
            #pragma unroll
            for (int m = 1; m < 16; m <<= 1)            // xor 1/2/4/8 -> DPP
                #pragma unroll
                for (int j = 0; j < 4; ++j) pr[j] += __shfl_xor(pr[j], m);
            if (ln == 0) {
                #pragma unroll
                for (int j = 0; j < 4; ++j) alpw[wave][mt*16 + hi*4 + j] = pr[j];
            }
        }

        __syncthreads();   // #2: alpw ready, ep16 free for next b

        // ---- softmax + rw (shift-invariant; |logit| <= sum|ua| ~ 13) ----
        if (t < NEI) {
            float s8 = 0.f;
            #pragma unroll
            for (int w = 0; w < 8; ++w) s8 += alpw[w][t];
            float a = fmaf(-2.f, s8, sua);
            float p = __expf(a);
            float s = p;
            #pragma unroll
            for (int m = 1; m < 64; m <<= 1) s += __shfl_xor(s, m);
            out[(size_t)b * NEI + t] = fmaf(p, __builtin_amdgcn_rcpf(s), rw[(size_t)b * NEI + t]);
        }
        // next iteration's ep16 writes are fenced by barrier #1 of that iteration;
        // alpw(i) reads complete before barrier #1(i+1) passes (syncthreads waits all).
    }
}

// ---------------- launch ----------------

extern "C" void kernel_launch(void* const* d_in, const int* in_sizes, int n_in,
                              void* d_out, int out_size, void* d_ws, size_t ws_size,
                              hipStream_t stream) {
    const float* e_emb   = (const float*)d_in[0];
    const float* rw      = (const float*)d_in[1];
    const float* w_r_tab = (const float*)d_in[2];
    const float* zq_tab  = (const float*)d_in[3];
    const float* attn_W  = (const float*)d_in[4];
    const float* attn_b  = (const float*)d_in[5];
    const float* u_a_w   = (const float*)d_in[6];
    // d_in[7] = u_a_b: cancels in softmax, unused
    const int*   nei_rid = (const int*)d_in[8];
    const int*   q_rid   = (const int*)d_in[9];
    float* out = (float*)d_out;

    float* ws = (float*)d_ws;
    float* norm_t = ws;                             // 1001*128 f32
    float* tq_t   = norm_t + NR_W * DIM;            // 1000*256 f32
    ushort* bfrag = (ushort*)(tq_t + NR_Z * D2);    // 16*4*64*8 bf16
    float* suap   = (float*)(bfrag + 16*4*64*8);    // 1 f32

    k_norm<<<NR_W, DIM, 0, stream>>>(w_r_tab, norm_t);
    k_tq<<<NR_Z, D2, 0, stream>>>(zq_tab, attn_W, attn_b, tq_t);
    k_bfrag<<<dim3(16, 4), 64, 0, stream>>>(attn_W, bfrag);
    k_sua<<<1, 256, 0, stream>>>(u_a_w, suap);
    k_main<<<NB / BPB, 512, 0, stream>>>(e_emb, rw, nei_rid, q_rid,
                                         norm_t, tq_t, bfrag, suap, u_a_w, out);
}

// Round 8
// 135.788 us; speedup vs baseline: 1.1136x; 1.0586x over previous
//
#include <hip/hip_runtime.h>
#include <hip/hip_bf16.h>

#define NB    8192
#define NEI   64
#define DIM   128
#define D2    256
#define NR_W  1001   // 2*CNT_R+1
#define NR_Z  1000   // 2*CNT_R
#define EPB_LD 136   // bf16 elems per LDS row (128 + 8 pad)
#define C2L2E 2.8853900817779268f   // 2*log2(e): exp(2v) = exp2(C2L2E*v)

typedef __attribute__((ext_vector_type(8))) short bf16x8;   // 8 bf16 = 4 VGPR
typedef __attribute__((ext_vector_type(4))) float f32x4;
typedef __attribute__((ext_vector_type(4))) unsigned int u32x4;

// opaque 16B global load: asm-produced values cannot be rematerialized or
// sunk by the allocator (rounds 2-6 failure: compiler squeezed to the
// 64-VGPR tier, re-loading B-fragments from L2 inside the MFMA loop and
// serializing the projection loads). Untied "=v" vector output is accepted
// by gfx950 (R7's tied "+v" vector constraints are not).
#define GLOAD16(dst, addr, OFF) \
    asm volatile("global_load_dwordx4 %0, %1, off offset:" OFF \
                 : "=v"(dst) : "v"(addr))

__device__ __forceinline__ ushort f2bf(float x) {
    union { float f; unsigned u; } c; c.f = x;
    unsigned u = c.u;
    return (ushort)((u + 0x7fffu + ((u >> 16) & 1u)) >> 16);   // RNE
}

__device__ __forceinline__ unsigned pk2(float a, float b) {
    __hip_bfloat162 h = __float22bfloat162_rn(make_float2(a, b));  // v_cvt_pk_bf16_f32
    return *(unsigned*)&h;
}

__device__ __forceinline__ bf16x8 asbf(u32x4 v) {
    union { u32x4 a; bf16x8 b; } u; u.a = v; return u.b;
}
__device__ __forceinline__ float4 asf4(u32x4 v) {
    union { u32x4 a; float4 b; } u; u.a = v; return u.b;
}

// ---------------- precompute kernels ----------------

__global__ void k_norm(const float* __restrict__ w_r_table, float* __restrict__ norm_t) {
    int r = blockIdx.x;          // 0..1000
    int t = threadIdx.x;         // 0..127
    float v = w_r_table[r * DIM + t];
    float s = v * v;
    #pragma unroll
    for (int m = 1; m < 64; m <<= 1) s += __shfl_xor(s, m);
    __shared__ float sh[2];
    if ((t & 63) == 0) sh[t >> 6] = s;
    __syncthreads();
    float tot = sh[0] + sh[1];
    norm_t[r * DIM + t] = v / sqrtf(tot);
}

// Tq[r][o] = attn_W_b[o] + sum_{k<128} attn_W_w[o][k] * zq_table[r][k]
__global__ void k_tq(const float* __restrict__ zq_table, const float* __restrict__ W,
                     const float* __restrict__ bias, float* __restrict__ tq_t) {
    int r = blockIdx.x;          // 0..999
    int o = threadIdx.x;         // 0..255
    __shared__ float4 z4[32];
    if (o < 32) z4[o] = ((const float4*)(zq_table + r * DIM))[o];
    __syncthreads();
    const float4* wr = (const float4*)(W + o * D2);
    float acc = bias[o];
    #pragma unroll 8
    for (int i = 0; i < 32; ++i) {
        float4 wv = wr[i], zv = z4[i];
        acc += wv.x*zv.x + wv.y*zv.y + wv.z*zv.z + wv.w*zv.w;
    }
    tq_t[r * D2 + o] = acc;
}

// B fragments in mfma_16x16x32_bf16 order (layout verified rounds 2-6):
// bfrag[((ot*4+kt)*64 + lane)*8 + j] = W2[k][o], o = ot*16+(lane&15), k = kt*32+(lane>>4)*8+j
__global__ void k_bfrag(const float* __restrict__ W, ushort* __restrict__ bfrag) {
    int ot = blockIdx.x;         // 0..15
    int kt = blockIdx.y;         // 0..3
    int l  = threadIdx.x;        // 0..63
    int o  = ot * 16 + (l & 15);
    int k  = kt * 32 + (l >> 4) * 8;
    const float4* src = (const float4*)(W + o * D2 + DIM + k);
    float4 a = src[0], c = src[1];
    uint4 w;
    w.x = f2bf(a.x) | ((unsigned)f2bf(a.y) << 16);
    w.y = f2bf(a.z) | ((unsigned)f2bf(a.w) << 16);
    w.z = f2bf(c.x) | ((unsigned)f2bf(c.y) << 16);
    w.w = f2bf(c.z) | ((unsigned)f2bf(c.w) << 16);
    *(uint4*)(bfrag + ((ot * 4 + kt) * 64 + l) * 8) = w;
}

// SUA = sum(u_a_w)  (alpha = SUA - 2*sum(ua*r))
__global__ void k_sua(const float* __restrict__ u, float* __restrict__ sua) {
    int t = threadIdx.x;         // 0..255
    float v = u[t];
    #pragma unroll
    for (int m = 1; m < 64; m <<= 1) v += __shfl_xor(v, m);
    __shared__ float sh[4];
    if ((t & 63) == 0) sh[t >> 6] = v;
    __syncthreads();
    if (t == 0) sua[0] = sh[0] + sh[1] + sh[2] + sh[3];
}

// ---------------- main fused kernel: one b per block, 512 threads ----------------
// All hot loads (B-fragments, e rows, norm rows) are asm-opaque 16B loads:
// truly resident, all concurrently in flight. One vmcnt(0)+sched_barrier
// binds them (rule #18: sched_barrier stops hipcc hoisting consumers).

__global__ __launch_bounds__(512, 2) void k_main(
    const float* __restrict__ e_emb,    // (B,64,128)
    const float* __restrict__ rw,       // (B,64)
    const int*   __restrict__ nei_rid,  // (B,64)
    const int*   __restrict__ q_rid,    // (B,)
    const float* __restrict__ norm_t,   // (1001,128)
    const float* __restrict__ tq_t,     // (1000,256)
    const ushort* __restrict__ bfrag,   // (16,4,64,8) bf16
    const float* __restrict__ u_a_sum,  // scalar SUA
    const float* __restrict__ u_a_w,    // (256,)
    float* __restrict__ out)            // (B,64)
{
    __shared__ __align__(16) ushort ep16[NEI * EPB_LD];  // 17408 B
    __shared__ float alpw[8][NEI];                       // 2048 B

    const int t    = threadIdx.x;
    const int wave = t >> 6, lane = t & 63;
    const int ln   = lane & 15, hi = lane >> 4;
    const int rgrp = t >> 4, q4 = t & 15;                // proj: 16 lanes/row
    const int b    = blockIdx.x;

    // ---- issue opaque B-fragment loads first (L2-hot, 8x16B per lane) ----
    const char* bb0 = (const char*)bfrag + (((wave * 2) * 4 * 64) + lane) * 16;
    const char* bb1 = bb0 + 4096;
    u32x4 bq0, bq1, bq2, bq3, bq4, bq5, bq6, bq7;
    GLOAD16(bq0, bb0, "0");    GLOAD16(bq1, bb0, "1024");
    GLOAD16(bq2, bb0, "2048"); GLOAD16(bq3, bb0, "3072");
    GLOAD16(bq4, bb1, "0");    GLOAD16(bq5, bb1, "1024");
    GLOAD16(bq6, bb1, "2048"); GLOAD16(bq7, bb1, "3072");

    // ---- rids (consumed for addresses before asm e/n loads issue) ----
    const int rid0 = nei_rid[b * NEI + rgrp];
    const int rid1 = nei_rid[b * NEI + 32 + rgrp];
    const char* ea = (const char*)(e_emb + ((size_t)b * NEI + rgrp) * DIM + q4 * 8);
    const char* eb = (const char*)(e_emb + ((size_t)b * NEI + 32 + rgrp) * DIM + q4 * 8);
    const char* na = (const char*)(norm_t + rid0 * DIM + q4 * 8);
    const char* nb = (const char*)(norm_t + rid1 * DIM + q4 * 8);
    u32x4 qea0, qea1, qeb0, qeb1, qna0, qna1, qnb0, qnb1;
    GLOAD16(qea0, ea, "0");  GLOAD16(qea1, ea, "16");
    GLOAD16(qeb0, eb, "0");  GLOAD16(qeb1, eb, "16");
    GLOAD16(qna0, na, "0");  GLOAD16(qna1, na, "16");
    GLOAD16(qnb0, nb, "0");  GLOAD16(qnb1, nb, "16");

    // ---- epilogue/softmax scalars (normal loads; compiler waits are
    //      conservative-safe alongside asm loads: vmcnt completes in order) ----
    const int qr = q_rid[b];
    const float tq0 = tq_t[qr * D2 + wave * 32 + ln];
    const float tq1 = tq_t[qr * D2 + wave * 32 + 16 + ln];
    const float ua0 = u_a_w[wave * 32 + ln];
    const float ua1 = u_a_w[wave * 32 + 16 + ln];
    const float rwv = rw[(size_t)b * NEI + (t & 63)];
    const float sua = u_a_sum[0];

    // ---- bind ALL asm loads ----
    asm volatile("s_waitcnt vmcnt(0)" ::: "memory");
    __builtin_amdgcn_sched_barrier(0);

    const float4 ea0 = asf4(qea0), ea1 = asf4(qea1);
    const float4 eb0 = asf4(qeb0), eb1 = asf4(qeb1);
    const float4 na0 = asf4(qna0), na1 = asf4(qna1);
    const float4 nb0 = asf4(qnb0), nb1 = asf4(qnb1);

    // ---- pass 0: rows 0..31 ----
    {
        float part = ea0.x*na0.x + ea0.y*na0.y + ea0.z*na0.z + ea0.w*na0.w
                   + ea1.x*na1.x + ea1.y*na1.y + ea1.z*na1.z + ea1.w*na1.w;
        part += __shfl_xor(part, 1);
        part += __shfl_xor(part, 2);
        part += __shfl_xor(part, 4);
        part += __shfl_xor(part, 8);
        const float d = part;                 // full-row e . n
        float p0 = fmaf(-d, na0.x, ea0.x), p1 = fmaf(-d, na0.y, ea0.y);
        float p2 = fmaf(-d, na0.z, ea0.z), p3 = fmaf(-d, na0.w, ea0.w);
        float p4 = fmaf(-d, na1.x, ea1.x), p5 = fmaf(-d, na1.y, ea1.y);
        float p6 = fmaf(-d, na1.z, ea1.z), p7 = fmaf(-d, na1.w, ea1.w);
        uint4 w; w.x = pk2(p0,p1); w.y = pk2(p2,p3); w.z = pk2(p4,p5); w.w = pk2(p6,p7);
        *(uint4*)((char*)ep16 + rgrp * (EPB_LD*2) + q4 * 16) = w;
    }
    // ---- pass 1: rows 32..63 ----
    {
        float part = eb0.x*nb0.x + eb0.y*nb0.y + eb0.z*nb0.z + eb0.w*nb0.w
                   + eb1.x*nb1.x + eb1.y*nb1.y + eb1.z*nb1.z + eb1.w*nb1.w;
        part += __shfl_xor(part, 1);
        part += __shfl_xor(part, 2);
        part += __shfl_xor(part, 4);
        part += __shfl_xor(part, 8);
        const float d = part;
        float p0 = fmaf(-d, nb0.x, eb0.x), p1 = fmaf(-d, nb0.y, eb0.y);
        float p2 = fmaf(-d, nb0.z, eb0.z), p3 = fmaf(-d, nb0.w, eb0.w);
        float p4 = fmaf(-d, nb1.x, eb1.x), p5 = fmaf(-d, nb1.y, eb1.y);
        float p6 = fmaf(-d, nb1.z, eb1.z), p7 = fmaf(-d, nb1.w, eb1.w);
        uint4 w; w.x = pk2(p0,p1); w.y = pk2(p2,p3); w.z = pk2(p4,p5); w.w = pk2(p6,p7);
        *(uint4*)((char*)ep16 + (32 + rgrp) * (EPB_LD*2) + q4 * 16) = w;
    }

    __syncthreads();   // ep16 ready

    const bf16x8 bf00 = asbf(bq0), bf01 = asbf(bq1), bf02 = asbf(bq2), bf03 = asbf(bq3);
    const bf16x8 bf10 = asbf(bq4), bf11 = asbf(bq5), bf12 = asbf(bq6), bf13 = asbf(bq7);
    const float tqs0 = C2L2E * tq0, tqs1 = C2L2E * tq1;

    // ---- MFMA + fused epilogue per M-tile (wave owns 32 output cols) ----
    #pragma unroll
    for (int mt = 0; mt < 4; ++mt) {
        bf16x8 a_[4];
        #pragma unroll
        for (int kt = 0; kt < 4; ++kt)
            a_[kt] = *(const bf16x8*)&ep16[(mt*16 + ln) * EPB_LD + kt*32 + hi*8];
        f32x4 acc0 = (f32x4){0.f,0.f,0.f,0.f}, acc1 = (f32x4){0.f,0.f,0.f,0.f};
        acc0 = __builtin_amdgcn_mfma_f32_16x16x32_bf16(a_[0], bf00, acc0, 0, 0, 0);
        acc1 = __builtin_amdgcn_mfma_f32_16x16x32_bf16(a_[0], bf10, acc1, 0, 0, 0);
        acc0 = __builtin_amdgcn_mfma_f32_16x16x32_bf16(a_[1], bf01, acc0, 0, 0, 0);
        acc1 = __builtin_amdgcn_mfma_f32_16x16x32_bf16(a_[1], bf11, acc1, 0, 0, 0);
        acc0 = __builtin_amdgcn_mfma_f32_16x16x32_bf16(a_[2], bf02, acc0, 0, 0, 0);
        acc1 = __builtin_amdgcn_mfma_f32_16x16x32_bf16(a_[2], bf12, acc1, 0, 0, 0);
        acc0 = __builtin_amdgcn_mfma_f32_16x16x32_bf16(a_[3], bf03, acc0, 0, 0, 0);
        acc1 = __builtin_amdgcn_mfma_f32_16x16x32_bf16(a_[3], bf13, acc1, 0, 0, 0);
        // C/D: col(=o-dim) = ln, row(=neighbor) = mt*16 + hi*4 + j
        float pr[4];
        #pragma unroll
        for (int j = 0; j < 4; ++j) {
            float ex0 = __builtin_exp2f(fmaf(C2L2E, acc0[j], tqs0));
            float ex1 = __builtin_exp2f(fmaf(C2L2E, acc1[j], tqs1));
            float r0  = __builtin_amdgcn_rcpf(ex0 + 1.f);
            float r1  = __builtin_amdgcn_rcpf(ex1 + 1.f);
            pr[j] = fmaf(ua0, r0, ua1 * r1);
        }
        #pragma unroll
        for (int m = 1; m < 16; m <<= 1)            // xor 1/2/4/8 -> DPP
            #pragma unroll
            for (int j = 0; j < 4; ++j) pr[j] += __shfl_xor(pr[j], m);
        if (ln == 0) {
            #pragma unroll
            for (int j = 0; j < 4; ++j) alpw[wave][mt*16 + hi*4 + j] = pr[j];
        }
    }

    __syncthreads();   // alpw ready

    // ---- softmax + rw (shift-invariant; |logit| bounded by sum|ua|) ----
    if (t < NEI) {
        float s8 = 0.f;
        #pragma unroll
        for (int w = 0; w < 8; ++w) s8 += alpw[w][t];
        float a = fmaf(-2.f, s8, sua);
        float p = __expf(a);
        float s = p;
        #pragma unroll
        for (int m = 1; m < 64; m <<= 1) s += __shfl_xor(s, m);
        out[(size_t)b * NEI + t] = fmaf(p, __builtin_amdgcn_rcpf(s), rwv);
    }
}

// ---------------- launch ----------------

extern "C" void kernel_launch(void* const* d_in, const int* in_sizes, int n_in,
                              void* d_out, int out_size, void* d_ws, size_t ws_size,
                              hipStream_t stream) {
    const float* e_emb   = (const float*)d_in[0];
    const float* rw      = (const float*)d_in[1];
    const float* w_r_tab = (const float*)d_in[2];
    const float* zq_tab  = (const float*)d_in[3];
    const float* attn_W  = (const float*)d_in[4];
    const float* attn_b  = (const float*)d_in[5];
    const float* u_a_w   = (const float*)d_in[6];
    // d_in[7] = u_a_b: cancels in softmax, unused
    const int*   nei_rid = (const int*)d_in[8];
    const int*   q_rid   = (const int*)d_in[9];
    float* out = (float*)d_out;

    float* ws = (float*)d_ws;
    float* norm_t = ws;                             // 1001*128 f32
    float* tq_t   = norm_t + NR_W * DIM;            // 1000*256 f32
    ushort* bfrag = (ushort*)(tq_t + NR_Z * D2);    // 16*4*64*8 bf16
    float* suap   = (float*)(bfrag + 16*4*64*8);    // 1 f32

    k_norm<<<NR_W, DIM, 0, stream>>>(w_r_tab, norm_t);
    k_tq<<<NR_Z, D2, 0, stream>>>(zq_tab, attn_W, attn_b, tq_t);
    k_bfrag<<<dim3(16, 4), 64, 0, stream>>>(attn_W, bfrag);
    k_sua<<<1, 256, 0, stream>>>(u_a_w, suap);
    k_main<<<NB, 512, 0, stream>>>(e_emb, rw, nei_rid, q_rid,
                                   norm_t, tq_t, bfrag, suap, u_a_w, out);
}